// Round 4
// baseline (290.509 us; speedup 1.0000x reference)
//
#include <hip/hip_runtime.h>

#define TD_ 512
#define B_  32
#define H_  512
#define TE_ 2048

typedef __attribute__((ext_vector_type(8))) short bf16x8;
typedef __attribute__((ext_vector_type(4))) short bf16x4;
typedef __attribute__((ext_vector_type(4))) float f32x4;

__device__ __forceinline__ short f2b(float f){
  union { float f; unsigned u; } v; v.f = f;
  return (short)((v.u + 0x7fffu + ((v.u >> 16) & 1u)) >> 16);  // RNE f32->bf16
}

__device__ __forceinline__ void gload16(const void* g, void* l){
  __builtin_amdgcn_global_load_lds((const __attribute__((address_space(1))) void*)g,
                                   (__attribute__((address_space(3))) void*)l,
                                   16, 0, 0);
}

// outputs_hidden (TD,B,H) f32 -> Abf (B,TD,H) bf16
__global__ __launch_bounds__(256) void k_cvtA(const float* __restrict__ oh,
                                              short* __restrict__ Abf){
  long base = ((long)blockIdx.x * 256 + threadIdx.x) * 4;
  int t = (int)(base >> 14);
  int rem = (int)(base & 16383);
  int b = rem >> 9, h = rem & 511;
  f32x4 v = *(const f32x4*)(oh + base);
  bf16x4 o;
  o[0]=f2b(v[0]); o[1]=f2b(v[1]); o[2]=f2b(v[2]); o[3]=f2b(v[3]);
  *(bf16x4*)(Abf + (long)b*TD_*H_ + (long)t*H_ + h) = o;
}

// encoder_out (B,H,TE) f32 -> Ebf (B,H,TE) bf16 (cast) + Ebt (B,TE,H) bf16 (transposed)
__global__ __launch_bounds__(256) void k_prep(const float* __restrict__ E,
                                              short* __restrict__ Ebf,
                                              short* __restrict__ Ebt){
  __shared__ short tile[64][72];
  int b = blockIdx.z;
  int h0 = blockIdx.y << 6, e0 = blockIdx.x << 6;
  int y = threadIdx.x >> 2;      // 0..63
  int x = threadIdx.x & 3;       // 0..3
  const float* Ein = E + ((long)b*H_ + h0 + y)*TE_ + e0 + x*16;
  short* Eo = Ebf + ((long)b*H_ + h0 + y)*TE_ + e0 + x*16;
  #pragma unroll
  for (int q=0;q<2;q++){
    f32x4 v0 = *(const f32x4*)(Ein + q*8);
    f32x4 v1 = *(const f32x4*)(Ein + q*8 + 4);
    bf16x8 o;
    o[0]=f2b(v0[0]); o[1]=f2b(v0[1]); o[2]=f2b(v0[2]); o[3]=f2b(v0[3]);
    o[4]=f2b(v1[0]); o[5]=f2b(v1[1]); o[6]=f2b(v1[2]); o[7]=f2b(v1[3]);
    *(bf16x8*)(Eo + q*8) = o;
    *(bf16x8*)(&tile[y][x*16 + q*8]) = o;
  }
  __syncthreads();
  short* Ob = Ebt + ((long)b*TE_ + e0 + y)*H_ + h0 + x*16;
  bf16x8 u0, u1;
  #pragma unroll
  for (int i2=0;i2<8;i2++) u0[i2] = tile[x*16 + i2][y];
  #pragma unroll
  for (int i2=0;i2<8;i2++) u1[i2] = tile[x*16 + 8 + i2][y];
  *(bf16x8*)(Ob) = u0;
  *(bf16x8*)(Ob + 8) = u1;
}

// Double-buffered staging, BK=32. Tile [128][32] bf16 per buffer (8 KB).
// Chunk c in [0,512): row=c>>2, col16=c&3; source col inverse-swizzled by (row&3).
#define STAGE2(Adst, Bdst, Asrc, Bsrc, lda, ldb, k0)                        \
  _Pragma("unroll")                                                         \
  for (int p=0;p<2;p++){                                                    \
    int cb = (w*2+p)*64; int c = cb + lane;                                 \
    int row = c >> 2; int cs = (c & 3) ^ (row & 3);                         \
    gload16((Asrc) + (long)row*(lda) + (k0) + cs*8, (char*)(Adst) + cb*16); \
    gload16((Bsrc) + (long)row*(ldb) + (k0) + cs*8, (char*)(Bdst) + cb*16); \
  }

// GEMM1 + fused epilogue. A=Abf (B,TD,H), B=Ebt (B,TE,H).
__global__ __launch_bounds__(256) void k_scores(
    const short* __restrict__ Abf, const short* __restrict__ Ebt,
    const float* __restrict__ S, float* __restrict__ NS,
    short* __restrict__ att, float* __restrict__ rs){
  __shared__ short As[2][128*32];
  __shared__ short Bs[2][128*32];
  int b = blockIdx.z;
  int t0 = blockIdx.y << 7;
  int e0 = blockIdx.x << 7;
  int tid = threadIdx.x, lane = tid & 63, w = tid >> 6;
  int wr = w >> 1, wc = w & 1, g = lane >> 4, lr = lane & 15;

  const short* Ag = Abf + (long)b*TD_*H_ + (long)t0*H_;
  const short* Bg = Ebt + (long)b*TE_*H_ + (long)e0*H_;

  const f32x4 fz = {0.f,0.f,0.f,0.f};
  f32x4 acc[4][4];
  #pragma unroll
  for (int m=0;m<4;m++)
    #pragma unroll
    for (int n=0;n<4;n++) acc[m][n] = fz;

  STAGE2(As[0], Bs[0], Ag, Bg, H_, H_, 0);
  int cur = 0;
  for (int kt=0; kt<16; ++kt){
    __syncthreads();                       // buf[cur] loads landed (issued last iter), buf[cur^1] free
    if (kt+1 < 16) STAGE2(As[cur^1], Bs[cur^1], Ag, Bg, H_, H_, (kt+1)*32);
    bf16x8 af[4], bfr[4];
    #pragma unroll
    for (int m=0;m<4;m++){
      int r_ = wr*64 + m*16 + lr;
      af[m] = *(const bf16x8*)((const char*)As[cur] + r_*64 + ((g<<4) ^ ((r_ & 3) << 4)));
    }
    #pragma unroll
    for (int n=0;n<4;n++){
      int r_ = wc*64 + n*16 + lr;
      bfr[n] = *(const bf16x8*)((const char*)Bs[cur] + r_*64 + ((g<<4) ^ ((r_ & 3) << 4)));
    }
    #pragma unroll
    for (int m=0;m<4;m++)
      #pragma unroll
      for (int n=0;n<4;n++)
        acc[m][n] = __builtin_amdgcn_mfma_f32_16x16x32_bf16(af[m], bfr[n], acc[m][n], 0, 0, 0);
    cur ^= 1;
  }

  const float* Sb = S + (long)b*TD_*TE_;
  float* NSb = NS + (long)b*TD_*TE_;
  short* attb = att + (long)b*TD_*TE_;
  #pragma unroll
  for (int m=0;m<4;m++){
    #pragma unroll
    for (int r=0;r<4;r++){
      int t = t0 + wr*64 + m*16 + g*4 + r;
      float rp = 0.f;
      #pragma unroll
      for (int n=0;n<4;n++){
        int e = e0 + wc*64 + n*16 + lr;
        long off = (long)t*TE_ + e;
        float sv = Sb[off];
        float ta = __expf(acc[m][n][r]);
        NSb[off] = ta + sv;
        float av = ta * __builtin_amdgcn_rcpf(sv);
        attb[off] = f2b(av);
        rp += av;
      }
      rp += __shfl_xor(rp, 1);
      rp += __shfl_xor(rp, 2);
      rp += __shfl_xor(rp, 4);
      rp += __shfl_xor(rp, 8);
      if (lr == 0) atomicAdd(&rs[b*TD_ + t], rp);
    }
  }
}

// GEMM2: ctx[t,h] = (att[t,:].Ebf[h,:]) / rs[t], K=TE. Output (TD,B,H).
__global__ __launch_bounds__(256) void k_ctx(
    const short* __restrict__ att, const short* __restrict__ Ebf,
    const float* __restrict__ rs, float* __restrict__ ctx){
  __shared__ short As[2][128*32];
  __shared__ short Bs[2][128*32];
  int b = blockIdx.z;
  int t0 = blockIdx.y << 7;
  int h0 = blockIdx.x << 7;
  int tid = threadIdx.x, lane = tid & 63, w = tid >> 6;
  int wr = w >> 1, wc = w & 1, g = lane >> 4, lr = lane & 15;

  const short* Ag = att + (long)b*TD_*TE_ + (long)t0*TE_;
  const short* Bg = Ebf + (long)b*H_*TE_ + (long)h0*TE_;

  const f32x4 fz = {0.f,0.f,0.f,0.f};
  f32x4 acc[4][4];
  #pragma unroll
  for (int m=0;m<4;m++)
    #pragma unroll
    for (int n=0;n<4;n++) acc[m][n] = fz;

  STAGE2(As[0], Bs[0], Ag, Bg, TE_, TE_, 0);
  int cur = 0;
  for (int kt=0; kt<64; ++kt){
    __syncthreads();
    if (kt+1 < 64) STAGE2(As[cur^1], Bs[cur^1], Ag, Bg, TE_, TE_, (kt+1)*32);
    bf16x8 af[4], bfr[4];
    #pragma unroll
    for (int m=0;m<4;m++){
      int r_ = wr*64 + m*16 + lr;
      af[m] = *(const bf16x8*)((const char*)As[cur] + r_*64 + ((g<<4) ^ ((r_ & 3) << 4)));
    }
    #pragma unroll
    for (int n=0;n<4;n++){
      int r_ = wc*64 + n*16 + lr;
      bfr[n] = *(const bf16x8*)((const char*)Bs[cur] + r_*64 + ((g<<4) ^ ((r_ & 3) << 4)));
    }
    #pragma unroll
    for (int m=0;m<4;m++)
      #pragma unroll
      for (int n=0;n<4;n++)
        acc[m][n] = __builtin_amdgcn_mfma_f32_16x16x32_bf16(af[m], bfr[n], acc[m][n], 0, 0, 0);
    cur ^= 1;
  }

  #pragma unroll
  for (int m=0;m<4;m++){
    #pragma unroll
    for (int r=0;r<4;r++){
      int t = t0 + wr*64 + m*16 + g*4 + r;
      float inv = __builtin_amdgcn_rcpf(rs[b*TD_ + t]);
      #pragma unroll
      for (int n=0;n<4;n++){
        int h = h0 + wc*64 + n*16 + lr;
        ctx[(long)t*B_*H_ + (long)b*H_ + h] = acc[m][n][r] * inv;
      }
    }
  }
}

extern "C" void kernel_launch(void* const* d_in, const int* in_sizes, int n_in,
                              void* d_out, int out_size, void* d_ws, size_t ws_size,
                              hipStream_t stream){
  const float* oh = (const float*)d_in[0];   // (TD,B,H)
  const float* E  = (const float*)d_in[1];   // (B,H,TE)
  const float* S  = (const float*)d_in[2];   // (B,TD,TE)
  float* out_ctx = (float*)d_out;                       // (TD,B,H)
  float* out_ns  = out_ctx + (long)TD_*B_*H_;           // (B,TD,TE)

  char* ws = (char*)d_ws;
  size_t offEbt = 0;
  size_t offEbf = offEbt + (size_t)B_*TE_*H_*2;   // 64 MiB
  size_t offA   = offEbf + (size_t)B_*H_*TE_*2;   // 64 MiB
  size_t offAt  = offA   + (size_t)B_*TD_*H_*2;   // 16 MiB
  size_t offRs  = offAt  + (size_t)B_*TD_*TE_*2;  // 64 MiB
  short* Ebt  = (short*)(ws + offEbt);
  short* Ebf  = (short*)(ws + offEbf);
  short* Abf  = (short*)(ws + offA);
  short* attw = (short*)(ws + offAt);
  float* rsums= (float*)(ws + offRs);

  hipMemsetAsync(rsums, 0, (size_t)B_*TD_*4, stream);
  k_cvtA<<<dim3((TD_*B_*H_)/(256*4)), 256, 0, stream>>>(oh, Abf);
  k_prep<<<dim3(TE_/64, H_/64, B_), 256, 0, stream>>>(E, Ebf, Ebt);
  k_scores<<<dim3(TE_/128, TD_/128, B_), 256, 0, stream>>>(Abf, Ebt, S, out_ns, attw, rsums);
  k_ctx<<<dim3(H_/128, TD_/128, B_), 256, 0, stream>>>(attw, Ebf, rsums, out_ctx);
}

// Round 6
// 272.805 us; speedup vs baseline: 1.0649x; 1.0649x over previous
//
#include <hip/hip_runtime.h>

#define TD_ 512
#define B_  32
#define H_  512
#define TE_ 2048

typedef __attribute__((ext_vector_type(8))) short bf16x8;
typedef __attribute__((ext_vector_type(4))) short bf16x4;
typedef __attribute__((ext_vector_type(4))) float f32x4;

__device__ __forceinline__ short f2b(float f){
  union { float f; unsigned u; } v; v.f = f;
  return (short)((v.u + 0x7fffu + ((v.u >> 16) & 1u)) >> 16);  // RNE f32->bf16
}

__device__ __forceinline__ void gload16(const void* g, void* l){
  __builtin_amdgcn_global_load_lds((const __attribute__((address_space(1))) void*)g,
                                   (__attribute__((address_space(3))) void*)l,
                                   16, 0, 0);
}

// outputs_hidden (TD,B,H) f32 -> Abf (B,TD,H) bf16
__global__ __launch_bounds__(256) void k_cvtA(const float* __restrict__ oh,
                                              short* __restrict__ Abf){
  long base = ((long)blockIdx.x * 256 + threadIdx.x) * 4;
  int t = (int)(base >> 14);
  int rem = (int)(base & 16383);
  int b = rem >> 9, h = rem & 511;
  f32x4 v = *(const f32x4*)(oh + base);
  bf16x4 o;
  o[0]=f2b(v[0]); o[1]=f2b(v[1]); o[2]=f2b(v[2]); o[3]=f2b(v[3]);
  *(bf16x4*)(Abf + (long)b*TD_*H_ + (long)t*H_ + h) = o;
}

// encoder_out (B,H,TE) f32 -> Ebf (B,H,TE) bf16 (cast) + Ebt (B,TE,H) bf16 (transposed)
__global__ __launch_bounds__(256) void k_prep(const float* __restrict__ E,
                                              short* __restrict__ Ebf,
                                              short* __restrict__ Ebt){
  __shared__ short tile[64][72];
  int b = blockIdx.z;
  int h0 = blockIdx.y << 6, e0 = blockIdx.x << 6;
  int y = threadIdx.x >> 2;      // 0..63
  int x = threadIdx.x & 3;       // 0..3
  const float* Ein = E + ((long)b*H_ + h0 + y)*TE_ + e0 + x*16;
  short* Eo = Ebf + ((long)b*H_ + h0 + y)*TE_ + e0 + x*16;
  #pragma unroll
  for (int q=0;q<2;q++){
    f32x4 v0 = *(const f32x4*)(Ein + q*8);
    f32x4 v1 = *(const f32x4*)(Ein + q*8 + 4);
    bf16x8 o;
    o[0]=f2b(v0[0]); o[1]=f2b(v0[1]); o[2]=f2b(v0[2]); o[3]=f2b(v0[3]);
    o[4]=f2b(v1[0]); o[5]=f2b(v1[1]); o[6]=f2b(v1[2]); o[7]=f2b(v1[3]);
    *(bf16x8*)(Eo + q*8) = o;
    *(bf16x8*)(&tile[y][x*16 + q*8]) = o;
  }
  __syncthreads();
  short* Ob = Ebt + ((long)b*TE_ + e0 + y)*H_ + h0 + x*16;
  bf16x8 u0, u1;
  #pragma unroll
  for (int i2=0;i2<8;i2++) u0[i2] = tile[x*16 + i2][y];
  #pragma unroll
  for (int i2=0;i2<8;i2++) u1[i2] = tile[x*16 + 8 + i2][y];
  *(bf16x8*)(Ob) = u0;
  *(bf16x8*)(Ob + 8) = u1;
}

// BK=64 staging into [128][64] bf16 tiles, source-inverse-swizzled (round-3, verified).
#define STAGE64(Adst, Bdst, Asrc, Bsrc, lda, ldb, k0)                        \
  _Pragma("unroll")                                                          \
  for (int p=0;p<4;p++){                                                     \
    int cb = (w*4+p)*64; int c = cb + lane;                                  \
    int row = c >> 3; int cs = (c & 7) ^ (row & 7);                          \
    gload16((Asrc) + (long)row*(lda) + (k0) + cs*8, (char*)(Adst) + cb*16);  \
    gload16((Bsrc) + (long)row*(ldb) + (k0) + cs*8, (char*)(Bdst) + cb*16);  \
  }

#define FRAG_READS(Abuf, Bbuf)                                                              \
    _Pragma("unroll")                                                                       \
    for (int ks=0;ks<2;ks++){                                                               \
      bf16x8 af[4], bfr[4];                                                                 \
      _Pragma("unroll")                                                                     \
      for (int m=0;m<4;m++){                                                                \
        int r_ = wr*64 + m*16 + lr;                                                         \
        af[m] = *(const bf16x8*)((const char*)(Abuf) + r_*128 + ((ks*64 + g*16) ^ ((r_ & 7) << 4))); \
      }                                                                                     \
      _Pragma("unroll")                                                                     \
      for (int n=0;n<4;n++){                                                                \
        int r_ = wc*64 + n*16 + lr;                                                         \
        bfr[n] = *(const bf16x8*)((const char*)(Bbuf) + r_*128 + ((ks*64 + g*16) ^ ((r_ & 7) << 4))); \
      }                                                                                     \
      _Pragma("unroll")                                                                     \
      for (int m=0;m<4;m++)                                                                 \
        _Pragma("unroll")                                                                   \
        for (int n=0;n<4;n++)                                                               \
          acc[m][n] = __builtin_amdgcn_mfma_f32_16x16x32_bf16(af[m], bfr[n], acc[m][n], 0, 0, 0); \
    }

// GEMM1 + fused vectorized epilogue. A=Abf (B,TD,H), B=Ebt (B,TE,H).
__global__ __launch_bounds__(256) void k_scores(
    const short* __restrict__ Abf, const short* __restrict__ Ebt,
    const float* __restrict__ S, float* __restrict__ NS,
    short* __restrict__ att, float* __restrict__ rs){
  __shared__ __align__(16) char smem[32768];
  short* As = (short*)smem;             // [128][64] bf16 = 16 KB
  short* Bs = (short*)(smem + 16384);   // [128][64] bf16 = 16 KB
  int b = blockIdx.z;
  int t0 = blockIdx.y << 7;
  int e0 = blockIdx.x << 7;
  int tid = threadIdx.x, lane = tid & 63, w = tid >> 6;
  int wr = w >> 1, wc = w & 1, g = lane >> 4, lr = lane & 15;

  const short* Ag = Abf + (long)b*TD_*H_ + (long)t0*H_;
  const short* Bg = Ebt + (long)b*TE_*H_ + (long)e0*H_;

  const f32x4 fz = {0.f,0.f,0.f,0.f};
  f32x4 acc[4][4];
  #pragma unroll
  for (int m=0;m<4;m++)
    #pragma unroll
    for (int n=0;n<4;n++) acc[m][n] = fz;

  for (int k0=0;k0<H_;k0+=64){
    __syncthreads();
    STAGE64(As, Bs, Ag, Bg, H_, H_, k0);
    __syncthreads();
    FRAG_READS(As, Bs);
  }

  __syncthreads();                       // all GEMM LDS reads done; reuse As region
  float* ep = (float*)(smem + (w << 12));  // 4 KB per wave: [16][64] f32, col XOR (tr<<2)

  const float* Sb = S + (long)b*TD_*TE_;
  float* NSb = NS + (long)b*TD_*TE_;
  short* attb = att + (long)b*TD_*TE_;

  #pragma unroll
  for (int m=0;m<4;m++){
    #pragma unroll
    for (int n=0;n<4;n++){
      #pragma unroll
      for (int r=0;r<4;r++){
        int tr = g*4 + r;
        ep[tr*64 + ((n*16 + lr) ^ (tr << 2))] = acc[m][n][r];
      }
    }
    __syncthreads();                     // publish ep writes before typed-vector read-back
    #pragma unroll
    for (int j=0;j<4;j++){
      int tr = j*4 + (lane >> 4);
      int el = (lane & 15) * 4;
      f32x4 c4 = *(const f32x4*)(ep + tr*64 + (el ^ (tr << 2)));
      int t = t0 + wr*64 + m*16 + tr;
      long off = (long)t*TE_ + e0 + wc*64 + el;
      f32x4 sv = *(const f32x4*)(Sb + off);
      f32x4 ns; bf16x4 ab; float rp = 0.f;
      #pragma unroll
      for (int i=0;i<4;i++){
        float ta = __expf(c4[i]);
        ns[i] = ta + sv[i];
        float av = ta * __builtin_amdgcn_rcpf(sv[i]);
        ab[i] = f2b(av);
        rp += av;
      }
      *(f32x4*)(NSb + off) = ns;
      *(bf16x4*)(attb + off) = ab;
      rp += __shfl_xor(rp, 1);
      rp += __shfl_xor(rp, 2);
      rp += __shfl_xor(rp, 4);
      rp += __shfl_xor(rp, 8);
      if ((lane & 15) == 0) atomicAdd(&rs[b*TD_ + t], rp);
    }
    __syncthreads();                     // region reused next m
  }
}

// GEMM2: ctx[t,h] = (att[t,:].Ebf[h,:]) / rs[t], K=TE. Output (TD,B,H), vectorized store.
__global__ __launch_bounds__(256) void k_ctx(
    const short* __restrict__ att, const short* __restrict__ Ebf,
    const float* __restrict__ rs, float* __restrict__ ctx){
  __shared__ __align__(16) char smem[32768];
  short* As = (short*)smem;
  short* Bs = (short*)(smem + 16384);
  int b = blockIdx.z;
  int t0 = blockIdx.y << 7;
  int h0 = blockIdx.x << 7;
  int tid = threadIdx.x, lane = tid & 63, w = tid >> 6;
  int wr = w >> 1, wc = w & 1, g = lane >> 4, lr = lane & 15;

  const short* Ag = att + (long)b*TD_*TE_ + (long)t0*TE_;
  const short* Bg = Ebf + (long)b*H_*TE_ + (long)h0*TE_;

  const f32x4 fz = {0.f,0.f,0.f,0.f};
  f32x4 acc[4][4];
  #pragma unroll
  for (int m=0;m<4;m++)
    #pragma unroll
    for (int n=0;n<4;n++) acc[m][n] = fz;

  for (int k0=0;k0<TE_;k0+=64){
    __syncthreads();
    STAGE64(As, Bs, Ag, Bg, TE_, TE_, k0);
    __syncthreads();
    FRAG_READS(As, Bs);
  }

  __syncthreads();
  float* ep = (float*)(smem + (w << 12));

  #pragma unroll
  for (int m=0;m<4;m++){
    #pragma unroll
    for (int n=0;n<4;n++){
      #pragma unroll
      for (int r=0;r<4;r++){
        int tr = g*4 + r;
        ep[tr*64 + ((n*16 + lr) ^ (tr << 2))] = acc[m][n][r];
      }
    }
    __syncthreads();                     // publish ep writes before read-back
    #pragma unroll
    for (int j=0;j<4;j++){
      int tr = j*4 + (lane >> 4);
      int hl = (lane & 15) * 4;
      f32x4 c4 = *(const f32x4*)(ep + tr*64 + (hl ^ (tr << 2)));
      int t = t0 + wr*64 + m*16 + tr;
      float inv = __builtin_amdgcn_rcpf(rs[b*TD_ + t]);
      c4[0]*=inv; c4[1]*=inv; c4[2]*=inv; c4[3]*=inv;
      *(f32x4*)(ctx + (long)t*B_*H_ + (long)b*H_ + h0 + wc*64 + hl) = c4;
    }
    __syncthreads();
  }
}

extern "C" void kernel_launch(void* const* d_in, const int* in_sizes, int n_in,
                              void* d_out, int out_size, void* d_ws, size_t ws_size,
                              hipStream_t stream){
  const float* oh = (const float*)d_in[0];   // (TD,B,H)
  const float* E  = (const float*)d_in[1];   // (B,H,TE)
  const float* S  = (const float*)d_in[2];   // (B,TD,TE)
  float* out_ctx = (float*)d_out;                       // (TD,B,H)
  float* out_ns  = out_ctx + (long)TD_*B_*H_;           // (B,TD,TE)

  char* ws = (char*)d_ws;
  size_t offEbt = 0;
  size_t offEbf = offEbt + (size_t)B_*TE_*H_*2;   // 64 MiB
  size_t offA   = offEbf + (size_t)B_*H_*TE_*2;   // 64 MiB
  size_t offAt  = offA   + (size_t)B_*TD_*H_*2;   // 16 MiB
  size_t offRs  = offAt  + (size_t)B_*TD_*TE_*2;  // 64 MiB
  short* Ebt  = (short*)(ws + offEbt);
  short* Ebf  = (short*)(ws + offEbf);
  short* Abf  = (short*)(ws + offA);
  short* attw = (short*)(ws + offAt);
  float* rsums= (float*)(ws + offRs);

  hipMemsetAsync(rsums, 0, (size_t)B_*TD_*4, stream);
  k_cvtA<<<dim3((TD_*B_*H_)/(256*4)), 256, 0, stream>>>(oh, Abf);
  k_prep<<<dim3(TE_/64, H_/64, B_), 256, 0, stream>>>(E, Ebf, Ebt);
  k_scores<<<dim3(TE_/128, TD_/128, B_), 256, 0, stream>>>(Abf, Ebt, S, out_ns, attw, rsums);
  k_ctx<<<dim3(H_/128, TD_/128, B_), 256, 0, stream>>>(attw, Ebf, rsums, out_ctx);
}

// Round 7
// 265.385 us; speedup vs baseline: 1.0947x; 1.0280x over previous
//
#include <hip/hip_runtime.h>

#define TD_ 512
#define B_  32
#define H_  512
#define TE_ 2048

typedef __attribute__((ext_vector_type(8))) short bf16x8;
typedef __attribute__((ext_vector_type(4))) short bf16x4;
typedef __attribute__((ext_vector_type(4))) float f32x4;

__device__ __forceinline__ short f2b(float f){
  union { float f; unsigned u; } v; v.f = f;
  return (short)((v.u + 0x7fffu + ((v.u >> 16) & 1u)) >> 16);  // RNE f32->bf16
}

__device__ __forceinline__ void gload16(const void* g, void* l){
  __builtin_amdgcn_global_load_lds((const __attribute__((address_space(1))) void*)g,
                                   (__attribute__((address_space(3))) void*)l,
                                   16, 0, 0);
}

// outputs_hidden (TD,B,H) f32 -> Abf (B,TD,H) bf16
__global__ __launch_bounds__(256) void k_cvtA(const float* __restrict__ oh,
                                              short* __restrict__ Abf){
  long base = ((long)blockIdx.x * 256 + threadIdx.x) * 4;
  int t = (int)(base >> 14);
  int rem = (int)(base & 16383);
  int b = rem >> 9, h = rem & 511;
  f32x4 v = *(const f32x4*)(oh + base);
  bf16x4 o;
  o[0]=f2b(v[0]); o[1]=f2b(v[1]); o[2]=f2b(v[2]); o[3]=f2b(v[3]);
  *(bf16x4*)(Abf + (long)b*TD_*H_ + (long)t*H_ + h) = o;
}

// encoder_out (B,H,TE) f32 -> Ebf (B,H,TE) bf16 (cast) + Ebt (B,TE,H) bf16 (transposed)
__global__ __launch_bounds__(256) void k_prep(const float* __restrict__ E,
                                              short* __restrict__ Ebf,
                                              short* __restrict__ Ebt){
  __shared__ short tile[64][72];
  int b = blockIdx.z;
  int h0 = blockIdx.y << 6, e0 = blockIdx.x << 6;
  int y = threadIdx.x >> 2;      // 0..63
  int x = threadIdx.x & 3;       // 0..3
  const float* Ein = E + ((long)b*H_ + h0 + y)*TE_ + e0 + x*16;
  short* Eo = Ebf + ((long)b*H_ + h0 + y)*TE_ + e0 + x*16;
  #pragma unroll
  for (int q=0;q<2;q++){
    f32x4 v0 = *(const f32x4*)(Ein + q*8);
    f32x4 v1 = *(const f32x4*)(Ein + q*8 + 4);
    bf16x8 o;
    o[0]=f2b(v0[0]); o[1]=f2b(v0[1]); o[2]=f2b(v0[2]); o[3]=f2b(v0[3]);
    o[4]=f2b(v1[0]); o[5]=f2b(v1[1]); o[6]=f2b(v1[2]); o[7]=f2b(v1[3]);
    *(bf16x8*)(Eo + q*8) = o;
    *(bf16x8*)(&tile[y][x*16 + q*8]) = o;
  }
  __syncthreads();
  short* Ob = Ebt + ((long)b*TE_ + e0 + y)*H_ + h0 + x*16;
  bf16x8 u0, u1;
  #pragma unroll
  for (int i2=0;i2<8;i2++) u0[i2] = tile[x*16 + i2][y];
  #pragma unroll
  for (int i2=0;i2<8;i2++) u1[i2] = tile[x*16 + 8 + i2][y];
  *(bf16x8*)(Ob) = u0;
  *(bf16x8*)(Ob + 8) = u1;
}

// BK=64 staging into [128][64] bf16 tiles, source-inverse-swizzled (round-3, verified).
#define STAGE64(Adst, Bdst, Asrc, Bsrc, lda, ldb, k0)                        \
  _Pragma("unroll")                                                          \
  for (int p=0;p<4;p++){                                                     \
    int cb = (w*4+p)*64; int c = cb + lane;                                  \
    int row = c >> 3; int cs = (c & 7) ^ (row & 7);                          \
    gload16((Asrc) + (long)row*(lda) + (k0) + cs*8, (char*)(Adst) + cb*16);  \
    gload16((Bsrc) + (long)row*(ldb) + (k0) + cs*8, (char*)(Bdst) + cb*16);  \
  }

#define FRAG_READS(Abuf, Bbuf)                                                              \
    _Pragma("unroll")                                                                       \
    for (int ks=0;ks<2;ks++){                                                               \
      bf16x8 af[4], bfr[4];                                                                 \
      _Pragma("unroll")                                                                     \
      for (int m=0;m<4;m++){                                                                \
        int r_ = wr*64 + m*16 + lr;                                                         \
        af[m] = *(const bf16x8*)((const char*)(Abuf) + r_*128 + ((ks*64 + g*16) ^ ((r_ & 7) << 4))); \
      }                                                                                     \
      _Pragma("unroll")                                                                     \
      for (int n=0;n<4;n++){                                                                \
        int r_ = wc*64 + n*16 + lr;                                                         \
        bfr[n] = *(const bf16x8*)((const char*)(Bbuf) + r_*128 + ((ks*64 + g*16) ^ ((r_ & 7) << 4))); \
      }                                                                                     \
      _Pragma("unroll")                                                                     \
      for (int m=0;m<4;m++)                                                                 \
        _Pragma("unroll")                                                                   \
        for (int n=0;n<4;n++)                                                               \
          acc[m][n] = __builtin_amdgcn_mfma_f32_16x16x32_bf16(af[m], bfr[n], acc[m][n], 0, 0, 0); \
    }

// GEMM1 + fused vectorized epilogue. A=Abf (B,TD,H), B=Ebt (B,TE,H).
// Rowsum partials -> rsp[b][eblk][t] via plain stores (NO global atomics).
__global__ __launch_bounds__(256) void k_scores(
    const short* __restrict__ Abf, const short* __restrict__ Ebt,
    const float* __restrict__ S, float* __restrict__ NS,
    short* __restrict__ att, float* __restrict__ rsp){
  __shared__ __align__(16) char smem[32768];
  __shared__ float rsLds[2][128];       // [wc][row] single-writer partial rowsums
  short* As = (short*)smem;             // [128][64] bf16 = 16 KB
  short* Bs = (short*)(smem + 16384);   // [128][64] bf16 = 16 KB
  int b = blockIdx.z;
  int t0 = blockIdx.y << 7;
  int e0 = blockIdx.x << 7;
  int tid = threadIdx.x, lane = tid & 63, w = tid >> 6;
  int wr = w >> 1, wc = w & 1, g = lane >> 4, lr = lane & 15;

  const short* Ag = Abf + (long)b*TD_*H_ + (long)t0*H_;
  const short* Bg = Ebt + (long)b*TE_*H_ + (long)e0*H_;

  const f32x4 fz = {0.f,0.f,0.f,0.f};
  f32x4 acc[4][4];
  #pragma unroll
  for (int m=0;m<4;m++)
    #pragma unroll
    for (int n=0;n<4;n++) acc[m][n] = fz;

  for (int k0=0;k0<H_;k0+=64){
    __syncthreads();
    STAGE64(As, Bs, Ag, Bg, H_, H_, k0);
    __syncthreads();
    FRAG_READS(As, Bs);
  }

  __syncthreads();                       // all GEMM LDS reads done; reuse As region
  float* ep = (float*)(smem + (w << 12));  // 4 KB per wave: [16][64] f32, col XOR (tr<<2)

  const float* Sb = S + (long)b*TD_*TE_;
  float* NSb = NS + (long)b*TD_*TE_;
  short* attb = att + (long)b*TD_*TE_;

  #pragma unroll
  for (int m=0;m<4;m++){
    #pragma unroll
    for (int n=0;n<4;n++){
      #pragma unroll
      for (int r=0;r<4;r++){
        int tr = g*4 + r;
        ep[tr*64 + ((n*16 + lr) ^ (tr << 2))] = acc[m][n][r];
      }
    }
    __syncthreads();                     // publish ep writes before typed-vector read-back
    #pragma unroll
    for (int j=0;j<4;j++){
      int tr = j*4 + (lane >> 4);
      int el = (lane & 15) * 4;
      f32x4 c4 = *(const f32x4*)(ep + tr*64 + (el ^ (tr << 2)));
      int tl = wr*64 + m*16 + tr;
      long off = (long)(t0 + tl)*TE_ + e0 + wc*64 + el;
      f32x4 sv = *(const f32x4*)(Sb + off);
      f32x4 ns; bf16x4 ab; float rp = 0.f;
      #pragma unroll
      for (int i=0;i<4;i++){
        float ta = __expf(c4[i]);
        ns[i] = ta + sv[i];
        float av = ta * __builtin_amdgcn_rcpf(sv[i]);
        ab[i] = f2b(av);
        rp += av;
      }
      *(f32x4*)(NSb + off) = ns;
      *(bf16x4*)(attb + off) = ab;
      rp += __shfl_xor(rp, 1);
      rp += __shfl_xor(rp, 2);
      rp += __shfl_xor(rp, 4);
      rp += __shfl_xor(rp, 8);
      if ((lane & 15) == 0) rsLds[wc][tl] = rp;   // single writer per (wc,row)
    }
    __syncthreads();                     // region reused next m
  }

  // block-partial rowsums -> rsp[b][eblk][t0..t0+127], coalesced plain store
  if (tid < 128){
    float v = rsLds[0][tid] + rsLds[1][tid];
    rsp[((long)b*16 + blockIdx.x)*TD_ + t0 + tid] = v;
  }
}

// GEMM2: ctx[t,h] = (att[t,:].Ebf[h,:]) * invRs[t], K=TE. Output (TD,B,H).
__global__ __launch_bounds__(256) void k_ctx(
    const short* __restrict__ att, const short* __restrict__ Ebf,
    const float* __restrict__ rsp, float* __restrict__ ctx){
  __shared__ __align__(16) char smem[32768];
  __shared__ float invRs[128];
  short* As = (short*)smem;
  short* Bs = (short*)(smem + 16384);
  int b = blockIdx.z;
  int t0 = blockIdx.y << 7;
  int h0 = blockIdx.x << 7;
  int tid = threadIdx.x, lane = tid & 63, w = tid >> 6;
  int wr = w >> 1, wc = w & 1, g = lane >> 4, lr = lane & 15;

  // reduce 16 per-eblk partials -> invRs (published by the first GEMM barrier)
  if (tid < 128){
    float s = 0.f;
    #pragma unroll
    for (int k=0;k<16;k++) s += rsp[((long)b*16 + k)*TD_ + t0 + tid];
    invRs[tid] = __builtin_amdgcn_rcpf(s);
  }

  const short* Ag = att + (long)b*TD_*TE_ + (long)t0*TE_;
  const short* Bg = Ebf + (long)b*H_*TE_ + (long)h0*TE_;

  const f32x4 fz = {0.f,0.f,0.f,0.f};
  f32x4 acc[4][4];
  #pragma unroll
  for (int m=0;m<4;m++)
    #pragma unroll
    for (int n=0;n<4;n++) acc[m][n] = fz;

  for (int k0=0;k0<TE_;k0+=64){
    __syncthreads();
    STAGE64(As, Bs, Ag, Bg, TE_, TE_, k0);
    __syncthreads();
    FRAG_READS(As, Bs);
  }

  __syncthreads();
  float* ep = (float*)(smem + (w << 12));

  #pragma unroll
  for (int m=0;m<4;m++){
    #pragma unroll
    for (int n=0;n<4;n++){
      #pragma unroll
      for (int r=0;r<4;r++){
        int tr = g*4 + r;
        ep[tr*64 + ((n*16 + lr) ^ (tr << 2))] = acc[m][n][r];
      }
    }
    __syncthreads();                     // publish ep writes before read-back
    #pragma unroll
    for (int j=0;j<4;j++){
      int tr = j*4 + (lane >> 4);
      int hl = (lane & 15) * 4;
      f32x4 c4 = *(const f32x4*)(ep + tr*64 + (hl ^ (tr << 2)));
      int tl = wr*64 + m*16 + tr;
      float inv = invRs[tl];
      c4[0]*=inv; c4[1]*=inv; c4[2]*=inv; c4[3]*=inv;
      *(f32x4*)(ctx + (long)(t0 + tl)*B_*H_ + (long)b*H_ + h0 + wc*64 + hl) = c4;
    }
    __syncthreads();
  }
}

extern "C" void kernel_launch(void* const* d_in, const int* in_sizes, int n_in,
                              void* d_out, int out_size, void* d_ws, size_t ws_size,
                              hipStream_t stream){
  const float* oh = (const float*)d_in[0];   // (TD,B,H)
  const float* E  = (const float*)d_in[1];   // (B,H,TE)
  const float* S  = (const float*)d_in[2];   // (B,TD,TE)
  float* out_ctx = (float*)d_out;                       // (TD,B,H)
  float* out_ns  = out_ctx + (long)TD_*B_*H_;           // (B,TD,TE)

  char* ws = (char*)d_ws;
  size_t offEbt = 0;
  size_t offEbf = offEbt + (size_t)B_*TE_*H_*2;   // 64 MiB
  size_t offA   = offEbf + (size_t)B_*H_*TE_*2;   // 64 MiB
  size_t offAt  = offA   + (size_t)B_*TD_*H_*2;   // 16 MiB
  size_t offRsp = offAt  + (size_t)B_*TD_*TE_*2;  // 64 MiB
  short* Ebt  = (short*)(ws + offEbt);
  short* Ebf  = (short*)(ws + offEbf);
  short* Abf  = (short*)(ws + offA);
  short* attw = (short*)(ws + offAt);
  float* rsp  = (float*)(ws + offRsp);            // [B][16][TD] partials: 1 MiB

  k_cvtA<<<dim3((TD_*B_*H_)/(256*4)), 256, 0, stream>>>(oh, Abf);
  k_prep<<<dim3(TE_/64, H_/64, B_), 256, 0, stream>>>(E, Ebf, Ebt);
  k_scores<<<dim3(TE_/128, TD_/128, B_), 256, 0, stream>>>(Abf, Ebt, S, out_ns, attw, rsp);
  k_ctx<<<dim3(H_/128, TD_/128, B_), 256, 0, stream>>>(attw, Ebf, rsp, out_ctx);
}